// Round 1
// baseline (3526.078 us; speedup 1.0000x reference)
//
#include <hip/hip_runtime.h>
#include <math.h>

// Problem constants
#define NW    32768   // B*W = 512*64 windows
#define G     8       // windows per block
#define NBLK  (NW / G)
#define NT    256

// Dims
#define ND    172     // NODE_DIM = EDGE_DIM = TIME_DIM
#define EVD   347     // EVENT_DIM
#define HID   64
#define D2    128
#define MLPD  76

// LDS regions (floats):
//  RA: 8352 = max(ef 24*348, u 48*172, feat 8*384)
//  RB: 4128 = max(ev 24*172, h 48*64, attention scratch 2816)
#define RA_F  8352
#define RB_F  4128

__global__ __launch_bounds__(256) void tempme_fused(
    const int*   __restrict__ node_idx,      // (NW, 6)
    const int*   __restrict__ edge_idx,      // (NW, 3)
    const int*   __restrict__ cat_feat,      // (NW, 1)
    const float* __restrict__ t_records,     // (NW, 3)
    const float* __restrict__ edge_identify, // (NW, 3, 3)
    const float* __restrict__ node_embed,    // (10000, 172)
    const float* __restrict__ edge_embed,    // (200000, 172)
    const float* __restrict__ basis_freq,    // (172,)
    const float* __restrict__ phase,         // (172,)
    const float* __restrict__ lin_event_w,   // (172, 347)
    const float* __restrict__ lin_event_b,   // (172,)
    const float* __restrict__ gcn_w1,        // (64, 172)
    const float* __restrict__ gcn_b1,        // (64,)
    const float* __restrict__ gcn_w2,        // (64, 64)
    const float* __restrict__ gcn_b2,        // (64,)
    const float* __restrict__ att_w1_w,      // (128, 128)
    const float* __restrict__ att_w1_b,      // (128,)
    const float* __restrict__ att_w2_w,      // (128, 128)
    const float* __restrict__ att_w2_b,      // (128,)
    const float* __restrict__ att_m1_w,      // (64, 128)
    const float* __restrict__ att_m1_b,      // (64,)
    const float* __restrict__ att_m2_w,      // (64, 64)
    const float* __restrict__ att_m2_b,      // (64,)
    const float* __restrict__ mlp_w1,        // (76, 76)
    const float* __restrict__ mlp_b1,        // (76,)
    const float* __restrict__ mlp_w2,        // (64, 76)
    const float* __restrict__ mlp_b2,        // (64,)
    const float* __restrict__ mlp_w3,        // (1, 64)
    const float* __restrict__ mlp_b3,        // (1,)
    float*       __restrict__ out)           // (NW,)
{
  __shared__ __align__(16) float lds[RA_F + RB_F];
  float* RA = lds;          // ef[24][348] -> u[48][172] -> feat[8][384]
  float* RB = lds + RA_F;   // ev[24][172] -> h[48][64]  -> scratch

  const int tid = threadIdx.x;
  const int bw0 = blockIdx.x * G;

  // ---------------- phase 0: build event_f rows ef[24][348] ----------------
  for (int r = 0; r < 3 * G; ++r) {
    const int g   = r / 3;
    const int l   = r - 3 * g;
    const int bw  = bw0 + g;
    const int rid = bw * 3 + l;
    const int e   = edge_idx[rid];
    const float dt = t_records[bw * 3 + 2] - t_records[rid];
    const float* erow = edge_embed + (long)e * ND;
    for (int k = tid; k < EVD; k += NT) {
      float v;
      if (k < ND) {
        v = erow[k];
      } else if (k < ND + 3) {
        v = edge_identify[rid * 3 + (k - ND)];
      } else {
        const int d = k - (ND + 3);
        v = cosf(fmaf(dt, basis_freq[d], phase[d]));
      }
      RA[r * 348 + k] = v;
    }
  }
  __syncthreads();

  // ---------------- phase 1: event linear  ev[24][172] ----------------
  // thread o (o<172) computes ev[r][o] for all 24 rows.
  if (tid < ND) {
    float acc[24];
#pragma unroll
    for (int r = 0; r < 24; ++r) acc[r] = 0.f;
    const float* wrow = lin_event_w + tid * EVD;  // row not 16B-aligned -> scalar loads
    for (int k = 0; k < 344; k += 4) {
      const float w0 = wrow[k], w1 = wrow[k + 1], w2 = wrow[k + 2], w3 = wrow[k + 3];
#pragma unroll
      for (int r = 0; r < 24; ++r) {
        const float4 e4 = *(const float4*)&RA[r * 348 + k];  // broadcast across lanes
        acc[r] = fmaf(w0, e4.x, fmaf(w1, e4.y, fmaf(w2, e4.z, fmaf(w3, e4.w, acc[r]))));
      }
    }
    for (int k = 344; k < EVD; ++k) {
      const float w = wrow[k];
#pragma unroll
      for (int r = 0; r < 24; ++r) acc[r] = fmaf(w, RA[r * 348 + k], acc[r]);
    }
    const float bo = lin_event_b[tid];
#pragma unroll
    for (int r = 0; r < 24; ++r) RB[r * ND + tid] = acc[r] + bo;
  }
  __syncthreads();

  // ---------------- phase 2a: build u rows (both GINE directions) ----------------
  // u[(2r+0)] = src + relu(tgt + ev) ; u[(2r+1)] = tgt + relu(src + ev)
  for (int r = 0; r < 24; ++r) {
    const int g  = r / 3;
    const int l  = r - 3 * g;
    const int bw = bw0 + g;
    const int si = node_idx[bw * 6 + 2 * l];
    const int ti = node_idx[bw * 6 + 2 * l + 1];
    const float* srow = node_embed + (long)si * ND;
    const float* trow = node_embed + (long)ti * ND;
    if (tid < ND) {
      const float e = RB[r * ND + tid];
      const float s = srow[tid];
      const float t = trow[tid];
      RA[(2 * r + 0) * ND + tid] = s + fmaxf(t + e, 0.f);
      RA[(2 * r + 1) * ND + tid] = t + fmaxf(s + e, 0.f);
    }
  }
  __syncthreads();

  // ---------------- phase 2b: gcn layer 1: h[48][64] = relu(W1 u + b1) ----------------
  {
    const int j  = tid & 63;
    const int rg = tid >> 6;  // 4 row-groups of 12
    float acc[12];
#pragma unroll
    for (int i = 0; i < 12; ++i) acc[i] = 0.f;
    const float* wrow = gcn_w1 + j * ND;  // 688B rows, 16B aligned
    for (int k = 0; k < ND; k += 4) {
      const float4 w4 = *(const float4*)(wrow + k);
#pragma unroll
      for (int i = 0; i < 12; ++i) {
        const float4 u4 = *(const float4*)&RA[(rg * 12 + i) * ND + k];
        acc[i] = fmaf(w4.x, u4.x, fmaf(w4.y, u4.y, fmaf(w4.z, u4.z, fmaf(w4.w, u4.w, acc[i]))));
      }
    }
    const float b = gcn_b1[j];
#pragma unroll
    for (int i = 0; i < 12; ++i) RB[(rg * 12 + i) * HID + j] = fmaxf(acc[i] + b, 0.f);
  }
  __syncthreads();

  // ---------------- phase 2c: gcn layer 2 -> feat[8][3][128] ----------------
  {
    const int j  = tid & 63;
    const int rg = tid >> 6;
    float acc[12];
#pragma unroll
    for (int i = 0; i < 12; ++i) acc[i] = 0.f;
    const float* wrow = gcn_w2 + j * HID;
    for (int k = 0; k < HID; k += 4) {
      const float4 w4 = *(const float4*)(wrow + k);
#pragma unroll
      for (int i = 0; i < 12; ++i) {
        const float4 h4 = *(const float4*)&RB[(rg * 12 + i) * HID + k];
        acc[i] = fmaf(w4.x, h4.x, fmaf(w4.y, h4.y, fmaf(w4.z, h4.z, fmaf(w4.w, h4.w, acc[i]))));
      }
    }
    const float b = gcn_b2[j];
    __syncthreads();  // all reads of RB(h) done before... (reads above) -- and RA(u) reads finished in 2b barrier; safe to write feat now
#pragma unroll
    for (int i = 0; i < 12; ++i) {
      const int s   = rg * 12 + i;
      const int g   = s / 6;
      const int rem = s - 6 * g;
      const int l   = rem >> 1;
      const int dir = rem & 1;
      RA[g * 384 + l * 128 + dir * HID + j] = acc[i] + b;
    }
  }
  __syncthreads();

  // ---------------- phase 3: attention + MLP head, one window per wave-iter ----------------
  {
    const int wv   = tid >> 6;
    const int lane = tid & 63;
    float* sc_out = RB;          // 8*128
    float* sc_m1  = RB + 1024;   // 8*64
    float* sc_x   = RB + 1536;   // 8*80
    float* sc_h1  = RB + 2176;   // 8*80
    for (int it = 0; it < 2; ++it) {
      const int g  = wv * 2 + it;
      const int bw = bw0 + g;
      const float* fg = RA + g * 384;  // feat[g][l][:]

      // Wp = W1 @ src + b1 ; lane owns d = lane, lane+64
      float p0 = att_w1_b[lane], p1 = att_w1_b[lane + 64];
      {
        const float* r0 = att_w1_w + lane * D2;
        const float* r1 = att_w1_w + (lane + 64) * D2;
        for (int e = 0; e < D2; e += 4) {
          const float4 f4 = *(const float4*)&fg[256 + e];
          const float4 a4 = *(const float4*)(r0 + e);
          const float4 b4 = *(const float4*)(r1 + e);
          p0 = fmaf(a4.x, f4.x, fmaf(a4.y, f4.y, fmaf(a4.z, f4.z, fmaf(a4.w, f4.w, p0))));
          p1 = fmaf(b4.x, f4.x, fmaf(b4.y, f4.y, fmaf(b4.z, f4.z, fmaf(b4.w, f4.w, p1))));
        }
      }
      // Wq[k] = W2 @ feat[k] + b2, k = 0,1
      float q00 = att_w2_b[lane], q01 = att_w2_b[lane + 64];
      float q10 = q00, q11 = q01;
      {
        const float* r0 = att_w2_w + lane * D2;
        const float* r1 = att_w2_w + (lane + 64) * D2;
        for (int e = 0; e < D2; e += 4) {
          const float4 a4 = *(const float4*)(r0 + e);
          const float4 b4 = *(const float4*)(r1 + e);
          const float4 f0 = *(const float4*)&fg[e];
          const float4 f1 = *(const float4*)&fg[128 + e];
          q00 = fmaf(a4.x, f0.x, fmaf(a4.y, f0.y, fmaf(a4.z, f0.z, fmaf(a4.w, f0.w, q00))));
          q01 = fmaf(b4.x, f0.x, fmaf(b4.y, f0.y, fmaf(b4.z, f0.z, fmaf(b4.w, f0.w, q01))));
          q10 = fmaf(a4.x, f1.x, fmaf(a4.y, f1.y, fmaf(a4.z, f1.z, fmaf(a4.w, f1.w, q10))));
          q11 = fmaf(b4.x, f1.x, fmaf(b4.y, f1.y, fmaf(b4.z, f1.z, fmaf(b4.w, f1.w, q11))));
        }
      }
      // scores (2 keys) + softmax
      float s0 = p0 * q00 + p1 * q01;
      float s1 = p0 * q10 + p1 * q11;
#pragma unroll
      for (int off = 32; off >= 1; off >>= 1) {
        s0 += __shfl_xor(s0, off, 64);
        s1 += __shfl_xor(s1, off, 64);
      }
      const float mx = fmaxf(s0, s1);
      const float e0 = expf(s0 - mx), e1 = expf(s1 - mx);
      const float inv = 1.f / (e0 + e1);
      const float a0 = e0 * inv, a1 = e1 * inv;
      // out = src + a0*Wq0 + a1*Wq1
      sc_out[g * 128 + lane]      = fg[256 + lane]      + a0 * q00 + a1 * q10;
      sc_out[g * 128 + 64 + lane] = fg[256 + 64 + lane] + a0 * q01 + a1 * q11;
      __syncthreads();

      // m1 = relu(att_m1 @ out + b) ; lane owns j = lane
      float m1 = att_m1_b[lane];
      {
        const float* wr = att_m1_w + lane * D2;
        const float* ob = sc_out + g * 128;
        for (int d = 0; d < D2; d += 4) {
          const float4 w4 = *(const float4*)(wr + d);
          const float4 o4 = *(const float4*)&ob[d];
          m1 = fmaf(w4.x, o4.x, fmaf(w4.y, o4.y, fmaf(w4.z, o4.z, fmaf(w4.w, o4.w, m1))));
        }
      }
      sc_m1[g * 64 + lane] = fmaxf(m1, 0.f);
      __syncthreads();

      // h = att_m2 @ m1 + b
      float hv = att_m2_b[lane];
      {
        const float* wr = att_m2_w + lane * HID;
        const float* mb = sc_m1 + g * 64;
        for (int d = 0; d < HID; d += 4) {
          const float4 w4 = *(const float4*)(wr + d);
          const float4 m4 = *(const float4*)&mb[d];
          hv = fmaf(w4.x, m4.x, fmaf(w4.y, m4.y, fmaf(w4.z, m4.z, fmaf(w4.w, m4.w, hv))));
        }
      }
      // x = concat(h, one_hot(cat,12))
      sc_x[g * 80 + lane] = hv;
      if (lane < 12) {
        const int cat = cat_feat[bw];
        sc_x[g * 80 + 64 + lane] = (cat == lane) ? 1.f : 0.f;
      }
      __syncthreads();

      // h1 = relu(mlp_w1 @ x + b1) : 76 outputs
      const float* xb = sc_x + g * 80;
      {
        float h1a = mlp_b1[lane];
        const float* wr = mlp_w1 + lane * MLPD;  // 304B rows, 16B aligned
        for (int k = 0; k < MLPD; k += 4) {
          const float4 w4 = *(const float4*)(wr + k);
          const float4 x4 = *(const float4*)&xb[k];
          h1a = fmaf(w4.x, x4.x, fmaf(w4.y, x4.y, fmaf(w4.z, x4.z, fmaf(w4.w, x4.w, h1a))));
        }
        sc_h1[g * 80 + lane] = fmaxf(h1a, 0.f);
        if (lane < 12) {
          float h1b = mlp_b1[64 + lane];
          const float* wr2 = mlp_w1 + (64 + lane) * MLPD;
          for (int k = 0; k < MLPD; k += 4) {
            const float4 w4 = *(const float4*)(wr2 + k);
            const float4 x4 = *(const float4*)&xb[k];
            h1b = fmaf(w4.x, x4.x, fmaf(w4.y, x4.y, fmaf(w4.z, x4.z, fmaf(w4.w, x4.w, h1b))));
          }
          sc_h1[g * 80 + 64 + lane] = fmaxf(h1b, 0.f);
        }
      }
      __syncthreads();

      // h2 = relu(mlp_w2 @ h1 + b2) ; z = mlp_w3 @ h2 + b3 ; sigmoid
      float h2 = mlp_b2[lane];
      {
        const float* wr = mlp_w2 + lane * MLPD;
        const float* hb = sc_h1 + g * 80;
        for (int k = 0; k < MLPD; k += 4) {
          const float4 w4 = *(const float4*)(wr + k);
          const float4 h4 = *(const float4*)&hb[k];
          h2 = fmaf(w4.x, h4.x, fmaf(w4.y, h4.y, fmaf(w4.z, h4.z, fmaf(w4.w, h4.w, h2))));
        }
      }
      h2 = fmaxf(h2, 0.f);
      float zz = mlp_w3[lane] * h2;
#pragma unroll
      for (int off = 32; off >= 1; off >>= 1) zz += __shfl_xor(zz, off, 64);
      if (lane == 0) out[bw] = 1.f / (1.f + expf(-(zz + mlp_b3[0])));
      __syncthreads();
    }
  }
}

extern "C" void kernel_launch(void* const* d_in, const int* in_sizes, int n_in,
                              void* d_out, int out_size, void* d_ws, size_t ws_size,
                              hipStream_t stream) {
  tempme_fused<<<NBLK, NT, 0, stream>>>(
      (const int*)d_in[0],    // node_idx
      (const int*)d_in[1],    // edge_idx
      (const int*)d_in[2],    // cat_feat
      (const float*)d_in[3],  // t_records
      (const float*)d_in[4],  // edge_identify
      // d_in[5] cut_time_l unused by reference
      (const float*)d_in[6],  // node_embed
      (const float*)d_in[7],  // edge_embed
      (const float*)d_in[8],  // basis_freq
      (const float*)d_in[9],  // phase
      (const float*)d_in[10], (const float*)d_in[11],  // lin_event
      (const float*)d_in[12], (const float*)d_in[13],  // gcn1
      (const float*)d_in[14], (const float*)d_in[15],  // gcn2
      (const float*)d_in[16], (const float*)d_in[17],  // att_w1
      (const float*)d_in[18], (const float*)d_in[19],  // att_w2
      (const float*)d_in[20], (const float*)d_in[21],  // att_m1
      (const float*)d_in[22], (const float*)d_in[23],  // att_m2
      (const float*)d_in[24], (const float*)d_in[25],  // mlp1
      (const float*)d_in[26], (const float*)d_in[27],  // mlp2
      (const float*)d_in[28], (const float*)d_in[29],  // mlp3
      (float*)d_out);
}

// Round 2
// 3274.593 us; speedup vs baseline: 1.0768x; 1.0768x over previous
//
#include <hip/hip_runtime.h>
#include <math.h>

// Problem constants
#define NW    32768   // B*W = 512*64 windows
#define G     8       // windows per block
#define NBLK  (NW / G)
#define NT    256

// Dims
#define ND    172     // NODE_DIM = EDGE_DIM = TIME_DIM
#define EVD   347     // EVENT_DIM
#define HID   64
#define D2    128
#define MLPD  76

// LDS overlays (float offsets). Liveness:
//   O_EV  : ev[24][172] (phase1 out) -> u0[24][172] in-place (2a) ; [0..1536) reused as H1 (2b-p1)
//   O_EF  : ef[12][348] (phase0/1, two passes) -> u1[24][172] (2a)
//   O_H0  : h0[24][64] (2b-p0)
//   O_H1  : h1[24][64] over dead u0 rows
//   O_FEAT: feat[8][3][128] over dead u0/u1
//   O_SC  : phase-3 scratch (2816) over dead u1
#define O_EV   0       // 4128
#define O_EF   4128    // 4176 (ef) / 4128 (u1)
#define O_H0   8304    // 1536
#define O_H1   0       // 1536
#define O_FEAT 1536    // 3072  [1536..4608)
#define O_SC   4608    // 2816  [4608..7424)
#define LDS_F  9840    // 39360 B -> 4 blocks/CU

__global__ __launch_bounds__(256, 4) void tempme_fused(
    const int*   __restrict__ node_idx,      // (NW, 6)
    const int*   __restrict__ edge_idx,      // (NW, 3)
    const int*   __restrict__ cat_feat,      // (NW, 1)
    const float* __restrict__ t_records,     // (NW, 3)
    const float* __restrict__ edge_identify, // (NW, 3, 3)
    const float* __restrict__ node_embed,    // (10000, 172)
    const float* __restrict__ edge_embed,    // (200000, 172)
    const float* __restrict__ basis_freq,    // (172,)
    const float* __restrict__ phase,         // (172,)
    const float* __restrict__ lin_event_w,   // (172, 347)
    const float* __restrict__ lin_event_b,   // (172,)
    const float* __restrict__ gcn_w1,        // (64, 172)
    const float* __restrict__ gcn_b1,        // (64,)
    const float* __restrict__ gcn_w2,        // (64, 64)
    const float* __restrict__ gcn_b2,        // (64,)
    const float* __restrict__ att_w1_w,      // (128, 128)
    const float* __restrict__ att_w1_b,      // (128,)
    const float* __restrict__ att_w2_w,      // (128, 128)
    const float* __restrict__ att_w2_b,      // (128,)
    const float* __restrict__ att_m1_w,      // (64, 128)
    const float* __restrict__ att_m1_b,      // (64,)
    const float* __restrict__ att_m2_w,      // (64, 64)
    const float* __restrict__ att_m2_b,      // (64,)
    const float* __restrict__ mlp_w1,        // (76, 76)
    const float* __restrict__ mlp_b1,        // (76,)
    const float* __restrict__ mlp_w2,        // (64, 76)
    const float* __restrict__ mlp_b2,        // (64,)
    const float* __restrict__ mlp_w3,        // (1, 64)
    const float* __restrict__ mlp_b3,        // (1,)
    float*       __restrict__ out)           // (NW,)
{
  __shared__ __align__(16) float lds[LDS_F];
  const int tid = threadIdx.x;
  const int bw0 = blockIdx.x * G;

  // ============ phases 0+1: event features + event linear, 2 passes of 12 rows ============
  for (int p = 0; p < 2; ++p) {
    // phase 0: build ef[lr][0..347) for rows r = 12p..12p+11
    for (int lr = 0; lr < 12; ++lr) {
      const int r   = p * 12 + lr;
      const int g   = r / 3;
      const int l   = r - 3 * g;
      const int bw  = bw0 + g;
      const int rid = bw * 3 + l;
      const int e   = edge_idx[rid];
      const float dt = t_records[bw * 3 + 2] - t_records[rid];
      const float* erow = edge_embed + (long)e * ND;
      for (int k = tid; k < EVD; k += NT) {
        float v;
        if (k < ND) {
          v = erow[k];
        } else if (k < ND + 3) {
          v = edge_identify[rid * 3 + (k - ND)];
        } else {
          const int d = k - (ND + 3);
          v = cosf(fmaf(dt, basis_freq[d], phase[d]));
        }
        lds[O_EF + lr * 348 + k] = v;
      }
    }
    __syncthreads();

    // phase 1: ev[12p+i][tid] = lin_event_w[tid] . ef[i] + b[tid]
    if (tid < ND) {
      float acc[12];
#pragma unroll
      for (int i = 0; i < 12; ++i) acc[i] = 0.f;
      const float* wrow = lin_event_w + tid * EVD;
      for (int k = 0; k < 344; k += 4) {
        const float w0 = wrow[k], w1 = wrow[k + 1], w2 = wrow[k + 2], w3 = wrow[k + 3];
#pragma unroll
        for (int i = 0; i < 12; ++i) {
          const float4 e4 = *(const float4*)&lds[O_EF + i * 348 + k];  // wave broadcast
          acc[i] = fmaf(w0, e4.x, fmaf(w1, e4.y, fmaf(w2, e4.z, fmaf(w3, e4.w, acc[i]))));
        }
      }
      for (int k = 344; k < EVD; ++k) {
        const float w = wrow[k];
#pragma unroll
        for (int i = 0; i < 12; ++i) acc[i] = fmaf(w, lds[O_EF + i * 348 + k], acc[i]);
      }
      const float bo = lin_event_b[tid];
#pragma unroll
      for (int i = 0; i < 12; ++i) lds[O_EV + (p * 12 + i) * ND + tid] = acc[i] + bo;
    }
    __syncthreads();
  }

  // ============ phase 2a: u0 = s + relu(t+e) (in-place over ev); u1 = t + relu(s+e) ============
  for (int r = 0; r < 24; ++r) {
    const int g  = r / 3;
    const int l  = r - 3 * g;
    const int bw = bw0 + g;
    const int si = node_idx[bw * 6 + 2 * l];
    const int ti = node_idx[bw * 6 + 2 * l + 1];
    if (tid < ND) {
      const float e = lds[O_EV + r * ND + tid];
      const float s = node_embed[(long)si * ND + tid];
      const float t = node_embed[(long)ti * ND + tid];
      lds[O_EV + r * ND + tid] = s + fmaxf(t + e, 0.f);  // u0
      lds[O_EF + r * ND + tid] = t + fmaxf(s + e, 0.f);  // u1
    }
  }
  __syncthreads();

  // ============ phase 2b: h_d[r][j] = relu(gcn_w1[j] . u_d[r] + b1[j]), d=0,1 ============
  {
    const int j  = tid & 63;
    const int rg = tid >> 6;  // 4 groups x 6 rows
    for (int d = 0; d < 2; ++d) {
      const float* U = &lds[d == 0 ? O_EV : O_EF];
      float acc[6];
#pragma unroll
      for (int i = 0; i < 6; ++i) acc[i] = 0.f;
      const float* wrow = gcn_w1 + j * ND;  // 688B rows, 16B aligned
      for (int k = 0; k < ND; k += 4) {
        const float4 w4 = *(const float4*)(wrow + k);
#pragma unroll
        for (int i = 0; i < 6; ++i) {
          const float4 u4 = *(const float4*)&U[(rg * 6 + i) * ND + k];
          acc[i] = fmaf(w4.x, u4.x, fmaf(w4.y, u4.y, fmaf(w4.z, u4.z, fmaf(w4.w, u4.w, acc[i]))));
        }
      }
      const float b = gcn_b1[j];
      float* H = &lds[d == 0 ? O_H0 : O_H1];
#pragma unroll
      for (int i = 0; i < 6; ++i) H[(rg * 6 + i) * HID + j] = fmaxf(acc[i] + b, 0.f);
      __syncthreads();  // d=0: u0 reads complete before d=1 overwrites [0..1536) with h1
    }
  }

  // ============ phase 2c: feat[g][l][d*64+j] = gcn_w2[j] . h_d[3g+l] + b2[j] ============
  {
    const int j  = tid & 63;
    const int rg = tid >> 6;
    for (int d = 0; d < 2; ++d) {
      const float* H = &lds[d == 0 ? O_H0 : O_H1];
      float acc[6];
#pragma unroll
      for (int i = 0; i < 6; ++i) acc[i] = 0.f;
      const float* wrow = gcn_w2 + j * HID;
      for (int k = 0; k < HID; k += 4) {
        const float4 w4 = *(const float4*)(wrow + k);
#pragma unroll
        for (int i = 0; i < 6; ++i) {
          const float4 h4 = *(const float4*)&H[(rg * 6 + i) * HID + k];
          acc[i] = fmaf(w4.x, h4.x, fmaf(w4.y, h4.y, fmaf(w4.z, h4.z, fmaf(w4.w, h4.w, acc[i]))));
        }
      }
      const float b = gcn_b2[j];
#pragma unroll
      for (int i = 0; i < 6; ++i) {
        const int r = rg * 6 + i;
        const int g = r / 3;
        const int l = r - 3 * g;
        lds[O_FEAT + g * 384 + l * 128 + d * HID + j] = acc[i] + b;
      }
      // no barrier between d passes: feat slots disjoint, H regions disjoint from feat
    }
  }
  __syncthreads();

  // ============ phase 3: attention + MLP head (all LDS slots wave-private per g) ============
  {
    const int wv   = tid >> 6;
    const int lane = tid & 63;
    float* sc_out = &lds[O_SC];           // 8*128
    float* sc_m1  = &lds[O_SC + 1024];    // 8*64
    float* sc_x   = &lds[O_SC + 1536];    // 8*80
    float* sc_h1  = &lds[O_SC + 2176];    // 8*80
    for (int it = 0; it < 2; ++it) {
      const int g  = wv * 2 + it;
      const int bw = bw0 + g;
      const float* fg = &lds[O_FEAT + g * 384];

      // Wp = att_w1 @ src + b1 ; lane owns d = lane, lane+64
      float p0 = att_w1_b[lane], p1 = att_w1_b[lane + 64];
      {
        const float* r0 = att_w1_w + lane * D2;
        const float* r1 = att_w1_w + (lane + 64) * D2;
        for (int e = 0; e < D2; e += 4) {
          const float4 f4 = *(const float4*)&fg[256 + e];
          const float4 a4 = *(const float4*)(r0 + e);
          const float4 b4 = *(const float4*)(r1 + e);
          p0 = fmaf(a4.x, f4.x, fmaf(a4.y, f4.y, fmaf(a4.z, f4.z, fmaf(a4.w, f4.w, p0))));
          p1 = fmaf(b4.x, f4.x, fmaf(b4.y, f4.y, fmaf(b4.z, f4.z, fmaf(b4.w, f4.w, p1))));
        }
      }
      // Wq[k] = att_w2 @ feat[k] + b2, k = 0,1
      float q00 = att_w2_b[lane], q01 = att_w2_b[lane + 64];
      float q10 = q00, q11 = q01;
      {
        const float* r0 = att_w2_w + lane * D2;
        const float* r1 = att_w2_w + (lane + 64) * D2;
        for (int e = 0; e < D2; e += 4) {
          const float4 a4 = *(const float4*)(r0 + e);
          const float4 b4 = *(const float4*)(r1 + e);
          const float4 f0 = *(const float4*)&fg[e];
          const float4 f1 = *(const float4*)&fg[128 + e];
          q00 = fmaf(a4.x, f0.x, fmaf(a4.y, f0.y, fmaf(a4.z, f0.z, fmaf(a4.w, f0.w, q00))));
          q01 = fmaf(b4.x, f0.x, fmaf(b4.y, f0.y, fmaf(b4.z, f0.z, fmaf(b4.w, f0.w, q01))));
          q10 = fmaf(a4.x, f1.x, fmaf(a4.y, f1.y, fmaf(a4.z, f1.z, fmaf(a4.w, f1.w, q10))));
          q11 = fmaf(b4.x, f1.x, fmaf(b4.y, f1.y, fmaf(b4.z, f1.z, fmaf(b4.w, f1.w, q11))));
        }
      }
      // scores (2 keys) + softmax (wave reductions)
      float s0 = p0 * q00 + p1 * q01;
      float s1 = p0 * q10 + p1 * q11;
#pragma unroll
      for (int off = 32; off >= 1; off >>= 1) {
        s0 += __shfl_xor(s0, off, 64);
        s1 += __shfl_xor(s1, off, 64);
      }
      const float mx = fmaxf(s0, s1);
      const float e0 = expf(s0 - mx), e1 = expf(s1 - mx);
      const float inv = 1.f / (e0 + e1);
      const float a0 = e0 * inv, a1 = e1 * inv;
      // out = src + a0*Wq0 + a1*Wq1  (wave-private slot; same-wave RAW handled by lgkmcnt)
      sc_out[g * 128 + lane]      = fg[256 + lane]      + a0 * q00 + a1 * q10;
      sc_out[g * 128 + 64 + lane] = fg[256 + 64 + lane] + a0 * q01 + a1 * q11;

      // m1 = relu(att_m1 @ out + b)
      float m1 = att_m1_b[lane];
      {
        const float* wr = att_m1_w + lane * D2;
        const float* ob = sc_out + g * 128;
        for (int d = 0; d < D2; d += 4) {
          const float4 w4 = *(const float4*)(wr + d);
          const float4 o4 = *(const float4*)&ob[d];
          m1 = fmaf(w4.x, o4.x, fmaf(w4.y, o4.y, fmaf(w4.z, o4.z, fmaf(w4.w, o4.w, m1))));
        }
      }
      sc_m1[g * 64 + lane] = fmaxf(m1, 0.f);

      // h = att_m2 @ m1 + b
      float hv = att_m2_b[lane];
      {
        const float* wr = att_m2_w + lane * HID;
        const float* mb = sc_m1 + g * 64;
        for (int d = 0; d < HID; d += 4) {
          const float4 w4 = *(const float4*)(wr + d);
          const float4 m4 = *(const float4*)&mb[d];
          hv = fmaf(w4.x, m4.x, fmaf(w4.y, m4.y, fmaf(w4.z, m4.z, fmaf(w4.w, m4.w, hv))));
        }
      }
      // x = concat(h, one_hot(cat,12))
      sc_x[g * 80 + lane] = hv;
      if (lane < 12) {
        const int cat = cat_feat[bw];
        sc_x[g * 80 + 64 + lane] = (cat == lane) ? 1.f : 0.f;
      }

      // h1 = relu(mlp_w1 @ x + b1) : 76 outputs
      const float* xb = sc_x + g * 80;
      {
        float h1a = mlp_b1[lane];
        const float* wr = mlp_w1 + lane * MLPD;
        for (int k = 0; k < MLPD; k += 4) {
          const float4 w4 = *(const float4*)(wr + k);
          const float4 x4 = *(const float4*)&xb[k];
          h1a = fmaf(w4.x, x4.x, fmaf(w4.y, x4.y, fmaf(w4.z, x4.z, fmaf(w4.w, x4.w, h1a))));
        }
        sc_h1[g * 80 + lane] = fmaxf(h1a, 0.f);
        if (lane < 12) {
          float h1b = mlp_b1[64 + lane];
          const float* wr2 = mlp_w1 + (64 + lane) * MLPD;
          for (int k = 0; k < MLPD; k += 4) {
            const float4 w4 = *(const float4*)(wr2 + k);
            const float4 x4 = *(const float4*)&xb[k];
            h1b = fmaf(w4.x, x4.x, fmaf(w4.y, x4.y, fmaf(w4.z, x4.z, fmaf(w4.w, x4.w, h1b))));
          }
          sc_h1[g * 80 + 64 + lane] = fmaxf(h1b, 0.f);
        }
      }

      // h2 = relu(mlp_w2 @ h1 + b2) ; z = mlp_w3 @ h2 + b3 ; sigmoid
      float h2 = mlp_b2[lane];
      {
        const float* wr = mlp_w2 + lane * MLPD;
        const float* hb = sc_h1 + g * 80;
        for (int k = 0; k < MLPD; k += 4) {
          const float4 w4 = *(const float4*)(wr + k);
          const float4 h4 = *(const float4*)&hb[k];
          h2 = fmaf(w4.x, h4.x, fmaf(w4.y, h4.y, fmaf(w4.z, h4.z, fmaf(w4.w, h4.w, h2))));
        }
      }
      h2 = fmaxf(h2, 0.f);
      float zz = mlp_w3[lane] * h2;
#pragma unroll
      for (int off = 32; off >= 1; off >>= 1) zz += __shfl_xor(zz, off, 64);
      if (lane == 0) out[bw] = 1.f / (1.f + expf(-(zz + mlp_b3[0])));
    }
  }
}

extern "C" void kernel_launch(void* const* d_in, const int* in_sizes, int n_in,
                              void* d_out, int out_size, void* d_ws, size_t ws_size,
                              hipStream_t stream) {
  tempme_fused<<<NBLK, NT, 0, stream>>>(
      (const int*)d_in[0],    // node_idx
      (const int*)d_in[1],    // edge_idx
      (const int*)d_in[2],    // cat_feat
      (const float*)d_in[3],  // t_records
      (const float*)d_in[4],  // edge_identify
      // d_in[5] cut_time_l unused by reference
      (const float*)d_in[6],  // node_embed
      (const float*)d_in[7],  // edge_embed
      (const float*)d_in[8],  // basis_freq
      (const float*)d_in[9],  // phase
      (const float*)d_in[10], (const float*)d_in[11],  // lin_event
      (const float*)d_in[12], (const float*)d_in[13],  // gcn1
      (const float*)d_in[14], (const float*)d_in[15],  // gcn2
      (const float*)d_in[16], (const float*)d_in[17],  // att_w1
      (const float*)d_in[18], (const float*)d_in[19],  // att_w2
      (const float*)d_in[20], (const float*)d_in[21],  // att_m1
      (const float*)d_in[22], (const float*)d_in[23],  // att_m2
      (const float*)d_in[24], (const float*)d_in[25],  // mlp1
      (const float*)d_in[26], (const float*)d_in[27],  // mlp2
      (const float*)d_in[28], (const float*)d_in[29],  // mlp3
      (float*)d_out);
}